// Round 14
// baseline (307.609 us; speedup 1.0000x reference)
//
#include <hip/hip_runtime.h>
#include <hip/hip_bf16.h>
#include <cstddef>

// Problem constants (fixed-shape problem)
constexpr int N_NODES = 50000;
constexpr int N_EDGES = 800000;
constexpr int IN_DIM  = 128;
constexpr int HID     = 64;
constexpr int HEADS   = 4;
constexpr int F1      = HEADS * HID;  // 256
constexpr int EMB     = 128;
constexpr int N_GRAPHS = 64;

// per-head W1 fragment size (NT=4, KK=4): 4*4*64*8 bf16 elements
constexpr int W1_FRAG = 4 * 4 * 64 * 8;                      // 8192
// gemm12 LDS tile stride in bf16 elems: 264*2 = 528 B rows (16 B aligned for
// ds_read_b128; 132 dwords mod 32 = 4 -> ~2-way bank alias, free per m136)
constexpr int LDSB = 264;
// fused-aggregate LDS node-row stride: 4*128+8 elems = 1040 B (16 B aligned,
// 260 dwords mod 32 = 4 -> same mild alias class as LDSB)
constexpr int AXS  = HEADS * IN_DIM + 8;                     // 520
// bucketed CSR build: bucket regions allocated in arbitrary order (196-entry
// scan), off/offE computed per-bucket in LDS (r10 structure).
constexpr int NBUCK    = (N_NODES + 255) / 256;              // 196
constexpr int P1_CHUNK = 2048;                               // edges per hist/append block
constexpr int P1_BLOCKS = (N_EDGES + P1_CHUNK - 1) / P1_CHUNK; // 391
constexpr int AS_BLOCKS = N_NODES / 16;                      // 3125 (exact)
constexpr int AGG12_BLOCKS = N_NODES / 16;                   // 3125 (exact)
static_assert(N_NODES % 16 == 0, "16-row tiling assumes exact fit");
static_assert(N_NODES <= 65536, "u16 col requires node ids < 65536");
static_assert(16 * AXS <= 2 * 16 * LDSB, "ax plane must fit the uni buffer");

typedef __bf16 bf16x8 __attribute__((ext_vector_type(8)));
typedef __bf16 bf16x2 __attribute__((ext_vector_type(2)));
typedef float  f32x4  __attribute__((ext_vector_type(4)));
typedef float  f32x2  __attribute__((ext_vector_type(2)));

__device__ __forceinline__ float lrelu(float x) { return x > 0.f ? x : 0.2f * x; }
__device__ __forceinline__ float eluf(float x)  { return x > 0.f ? x : expm1f(x); }
__device__ __forceinline__ f32x2 s2(float s)    { return (f32x2){s, s}; }

// ---------------------------------------------------------------------------
// Pack a [K x 16*NT] submatrix of B (leading dim ld, origin col0) into
// per-lane MFMA B-fragments, split hi/lo bf16.
// ---------------------------------------------------------------------------
__device__ __forceinline__ void pack_frag(const float* __restrict__ B,
                                          __bf16* __restrict__ hi,
                                          __bf16* __restrict__ lo,
                                          int pblk, int NT, int KK, int ld, int col0) {
    const int gid = pblk * 256 + threadIdx.x;
    if (gid >= NT * KK * 64) return;
    const int lane = gid & 63;
    const int rem  = gid >> 6;
    const int kk   = rem % KK;
    const int t    = rem / KK;
    const int n    = col0 + t * 16 + (lane & 15);
    const int k0   = kk * 32 + (lane >> 4) * 8;
#pragma unroll
    for (int j = 0; j < 8; j++) {
        const float v = B[(size_t)(k0 + j) * ld + n];
        const __bf16 h = (__bf16)v;
        hi[(size_t)gid * 8 + j] = h;
        lo[(size_t)gid * 8 + j] = (__bf16)(v - (float)h);
    }
}

// ---------------------------------------------------------------------------
// prep: [bucket histogram (196 buckets, LDS-staged) | pack W1 | pack W2 |
// wst = W1^T·a per head].
// ---------------------------------------------------------------------------
__global__ __launch_bounds__(256) void prep_kernel(const int* __restrict__ ei,
                                                   int* __restrict__ bcnt,
                                                   const float* __restrict__ W1,
                                                   __bf16* __restrict__ B1h,
                                                   __bf16* __restrict__ B1l,
                                                   const float* __restrict__ W2,
                                                   __bf16* __restrict__ B2h,
                                                   __bf16* __restrict__ B2l,
                                                   const float* __restrict__ as1v,
                                                   const float* __restrict__ ad1v,
                                                   float* __restrict__ wst) {
    const int b = blockIdx.x;
    if (b < P1_BLOCKS) {
        __shared__ int lh[NBUCK];
        const int tid = threadIdx.x;
        for (int i = tid; i < NBUCK; i += 256) lh[i] = 0;
        __syncthreads();
        const int e0 = b * P1_CHUNK;
#pragma unroll
        for (int i = 0; i < P1_CHUNK / 256; i++) {
            const int e = e0 + i * 256 + tid;
            if (e < N_EDGES) atomicAdd(&lh[ei[N_EDGES + e] >> 8], 1);
        }
        __syncthreads();
        for (int i = tid; i < NBUCK; i += 256) {
            const int c = lh[i];
            if (c) atomicAdd(&bcnt[i], c);
        }
        return;
    }
    const int pb = b - P1_BLOCKS;
    if (pb < 16) {
        const int head = pb >> 2;
        pack_frag(W1, B1h + head * W1_FRAG, B1l + head * W1_FRAG,
                  pb & 3, 4, 4, F1, head * HID);
        return;
    }
    if (pb < 32) {
        pack_frag(W2, B2h, B2l, pb - 16, 8, 8, EMB, 0);
        return;
    }
    // wst[o][c] = sum_k W1[c][h*64+k] * a[h][k], o = (src?0:4)+h
    const int gid = (pb - 32) * 256 + threadIdx.x;  // 0..1023
    const int o = gid >> 7, c = gid & 127;
    const int h = o & 3;
    const float* av = (o < 4) ? as1v : ad1v;
    float s = 0.f;
#pragma unroll 8
    for (int k = 0; k < HID; k++)
        s += W1[(size_t)c * F1 + h * HID + k] * av[h * HID + k];
    wst[o * IN_DIM + c] = s;
}

// ---------------------------------------------------------------------------
// scan196: single-block exclusive scan over bucket counts -> gbase[197],
// seeds the append cursors gcur.
// ---------------------------------------------------------------------------
__global__ __launch_bounds__(256) void scan196_kernel(const int* __restrict__ bcnt,
                                                      int* __restrict__ gbase,
                                                      int* __restrict__ gcur) {
    __shared__ int sm[256];
    const int t = threadIdx.x;
    const int v = (t < NBUCK) ? bcnt[t] : 0;
    sm[t] = v;
    __syncthreads();
    int val = v;
#pragma unroll
    for (int o = 1; o < 256; o <<= 1) {
        const int add = (t >= o) ? sm[t - o] : 0;
        __syncthreads();
        val += add;
        sm[t] = val;
        __syncthreads();
    }
    if (t < NBUCK) { gbase[t] = val - v; gcur[t] = val - v; }
    if (t == NBUCK - 1) gbase[NBUCK] = val;
}

// ---------------------------------------------------------------------------
// proj_append: [rank-8 logit projection + x->bf16 emit | SINGLE-PASS bucketed
// edge append].
// ---------------------------------------------------------------------------
__global__ __launch_bounds__(256) void proj_append_kernel(
        const float* __restrict__ x, const float* __restrict__ wst,
        float* __restrict__ as_out, float* __restrict__ ad_out,
        __bf16* __restrict__ xb,
        const int* __restrict__ ei, int* __restrict__ gcur,
        unsigned* __restrict__ stage) {
    const int tid = threadIdx.x;
    if (blockIdx.x < AS_BLOCKS) {
        const int n   = blockIdx.x * 16 + (tid >> 4);
        const int l16 = tid & 15;
        const int d8  = l16 * 8;
        const float4 xa = *(const float4*)&x[(size_t)n * IN_DIM + d8];
        const float4 xc = *(const float4*)&x[(size_t)n * IN_DIM + d8 + 4];
        bf16x8 bw;
        bw[0] = (__bf16)xa.x; bw[1] = (__bf16)xa.y;
        bw[2] = (__bf16)xa.z; bw[3] = (__bf16)xa.w;
        bw[4] = (__bf16)xc.x; bw[5] = (__bf16)xc.y;
        bw[6] = (__bf16)xc.z; bw[7] = (__bf16)xc.w;
        *(bf16x8*)&xb[(size_t)n * IN_DIM + d8] = bw;
        float p[8];
#pragma unroll
        for (int o = 0; o < 8; o++) {
            const float4 wa = *(const float4*)&wst[o * IN_DIM + d8];
            const float4 wb = *(const float4*)&wst[o * IN_DIM + d8 + 4];
            p[o] = xa.x * wa.x + xa.y * wa.y + xa.z * wa.z + xa.w * wa.w
                 + xc.x * wb.x + xc.y * wb.y + xc.z * wb.z + xc.w * wb.w;
        }
#pragma unroll
        for (int off = 1; off < 16; off <<= 1) {
#pragma unroll
            for (int o = 0; o < 8; o++) p[o] += __shfl_xor(p[o], off);
        }
        if (l16 == 0) {
            *(float4*)&as_out[n * HEADS] = (float4){p[0], p[1], p[2], p[3]};
            *(float4*)&ad_out[n * HEADS] = (float4){p[4], p[5], p[6], p[7]};
        }
        return;
    }
    // single-pass bucketed append
    __shared__ int lhist[NBUCK];
    __shared__ int lbase[NBUCK];
    const int e0 = (blockIdx.x - AS_BLOCKS) * P1_CHUNK;
    for (int b = tid; b < NBUCK; b += 256) lhist[b] = 0;
    __syncthreads();
    unsigned pv[P1_CHUNK / 256];
    int      bk[P1_CHUNK / 256];
    int      rk[P1_CHUNK / 256];
#pragma unroll
    for (int i = 0; i < P1_CHUNK / 256; i++) {
        const int e = e0 + i * 256 + tid;
        if (e < N_EDGES) {
            const int s = ei[e], d = ei[N_EDGES + e];
            pv[i] = (unsigned)s | ((unsigned)d << 16);
            bk[i] = d >> 8;
            rk[i] = atomicAdd(&lhist[bk[i]], 1);
        } else {
            bk[i] = -1;
        }
    }
    __syncthreads();
    for (int b = tid; b < NBUCK; b += 256) {
        const int c = lhist[b];
        lbase[b] = c ? atomicAdd(&gcur[b], c) : 0;
    }
    __syncthreads();
#pragma unroll
    for (int i = 0; i < P1_CHUNK / 256; i++) {
        if (bk[i] >= 0) stage[lbase[bk[i]] + rk[i]] = pv[i];
    }
}

// ---------------------------------------------------------------------------
// distribute: one block per bucket. LDS node histogram + block scan ->
// off/offE; place col (u16) + w4 using LDS cursors.
// ---------------------------------------------------------------------------
__global__ __launch_bounds__(256) void distribute_kernel(
        const unsigned* __restrict__ stage, const int* __restrict__ gbase,
        const float* __restrict__ as1, const float* __restrict__ ad1,
        int* __restrict__ off, int* __restrict__ offE,
        unsigned short* __restrict__ col, float4* __restrict__ w4, int N) {
    __shared__ int lcnt[256];
    __shared__ int sm[256];
    __shared__ int lcur[256];
    const int t = threadIdx.x;
    const int b = blockIdx.x;
    const int wb = gbase[b], we = gbase[b + 1];
    lcnt[t] = 0;
    __syncthreads();
    for (int j = wb + t; j < we; j += 256)
        atomicAdd(&lcnt[(stage[j] >> 16) & 255], 1);
    __syncthreads();
    const int v = lcnt[t];
    sm[t] = v;
    __syncthreads();
    int val = v;
#pragma unroll
    for (int o = 1; o < 256; o <<= 1) {
        const int add = (t >= o) ? sm[t - o] : 0;
        __syncthreads();
        val += add;
        sm[t] = val;
        __syncthreads();
    }
    const int node = b * 256 + t;
    if (node < N) {
        off[node]  = wb + val - v;
        offE[node] = wb + val;
    }
    lcur[t] = wb + val - v;
    __syncthreads();
    for (int j = wb + t; j < we; j += 256) {
        const unsigned p = stage[j];
        const int s = (int)(p & 0xFFFFu);
        const int d = (int)(p >> 16);
        const int pos = atomicAdd(&lcur[d & 255], 1);
        const float4 a  = *(const float4*)&as1[s * HEADS];
        const float4 bb = *(const float4*)&ad1[d * HEADS];
        float4 o;
        o.x = __expf(lrelu(a.x + bb.x));
        o.y = __expf(lrelu(a.y + bb.y));
        o.z = __expf(lrelu(a.z + bb.z));
        o.w = __expf(lrelu(a.w + bb.w));
        col[pos] = (unsigned short)s;
        w4[pos] = o;
    }
}

// ---------------------------------------------------------------------------
// FUSED layer-1 aggregation + layer-1 GEMM + layer-2 GEMM, 16 rows/block.
// LDS diet (17.4 KB, sequential hi/lo staging) with the register-lifetime
// bug fixed: the lo plane is held in bf16 REGISTERS (lvk[4] = 16 VGPR)
// across the hi-preload barrier, so acc[4][8] (32 VGPR) dies at normalize
// exactly as in the proven r11 kernel. r12/r13 kept acc live across
// barriers -> natural VGPR ~95 > cap -> 91-428 MB scratch spill.
// ---------------------------------------------------------------------------
__global__ __launch_bounds__(256, 6) void agg_gemm12_kernel(
        const int* __restrict__ off, const int* __restrict__ offE,
        const unsigned short* __restrict__ col,
        const float4* __restrict__ w4, const __bf16* __restrict__ xb,
        const float* __restrict__ as1, const float* __restrict__ ad1,
        const __bf16* __restrict__ B1h, const __bf16* __restrict__ B1l,
        const float* __restrict__ b1,
        const __bf16* __restrict__ B2h, const __bf16* __restrict__ B2l,
        const float* __restrict__ avs, const float* __restrict__ avd,
        __bf16* __restrict__ g2b, float* __restrict__ as_out,
        float* __restrict__ ad_out, int M) {
    __shared__ __bf16 uni[2 * 16 * LDSB];    // 16,896 B (ax plane: 16,640 B)
    __shared__ float pps[4][16], pdd[4][16];
    __bf16* const ax  = uni;                 // [16][AXS] single hi/lo plane
    __bf16* const smh = uni;                 // [16][LDSB]
    __bf16* const sml = uni + 16 * LDSB;     // [16][LDSB]
    const int tid  = threadIdx.x;
    const int wave = tid >> 6, lane = tid & 63;
    const int quad = lane >> 4, l16 = lane & 15;
    const int row0 = blockIdx.x * 16;
    const int ln = wave * 4 + quad;          // local node 0..15
    const int w  = row0 + ln;                // global node (exact fit)
    const int d8 = l16 * 8;                  // this lane's 8 dims

    // ---- phase 0: gather-aggregate; one node per 16-lane group ----
    bf16x8 lvk[HEADS];                       // lo plane cache (16 VGPR)
    {
        float acc[HEADS][8];
        float z[HEADS];
        {   // self-loop
            const float4 asv = *(const float4*)&as1[w * HEADS];
            const float4 adv = *(const float4*)&ad1[w * HEADS];
            const float ws0 = __expf(lrelu(asv.x + adv.x));
            const float ws1 = __expf(lrelu(asv.y + adv.y));
            const float ws2 = __expf(lrelu(asv.z + adv.z));
            const float ws3 = __expf(lrelu(asv.w + adv.w));
            const bf16x8 xv = *(const bf16x8*)&xb[(size_t)w * IN_DIM + d8];
#pragma unroll
            for (int d = 0; d < 8; d++) {
                const float xf = (float)xv[d];
                acc[0][d] = ws0 * xf; acc[1][d] = ws1 * xf;
                acc[2][d] = ws2 * xf; acc[3][d] = ws3 * xf;
            }
            z[0] = ws0; z[1] = ws1; z[2] = ws2; z[3] = ws3;
        }
        const int jb = off[w], je = offE[w];
        int j = jb;
        for (; j + 3 < je; j += 4) {
            int    s[4];
            float4 ww[4];
            bf16x8 bv[4];
#pragma unroll
            for (int u = 0; u < 4; u++) s[u] = (int)col[j + u];
#pragma unroll
            for (int u = 0; u < 4; u++) ww[u] = w4[j + u];
#pragma unroll
            for (int u = 0; u < 4; u++)
                bv[u] = *(const bf16x8*)&xb[(size_t)s[u] * IN_DIM + d8];
#pragma unroll
            for (int u = 0; u < 4; u++) {
#pragma unroll
                for (int d = 0; d < 8; d++) {
                    const float xf = (float)bv[u][d];
                    acc[0][d] += ww[u].x * xf;
                    acc[1][d] += ww[u].y * xf;
                    acc[2][d] += ww[u].z * xf;
                    acc[3][d] += ww[u].w * xf;
                }
                z[0] += ww[u].x; z[1] += ww[u].y;
                z[2] += ww[u].z; z[3] += ww[u].w;
            }
        }
        for (; j < je; j++) {
            const int s0 = (int)col[j];
            const float4 w0 = w4[j];
            const bf16x8 b0 = *(const bf16x8*)&xb[(size_t)s0 * IN_DIM + d8];
#pragma unroll
            for (int d = 0; d < 8; d++) {
                const float xf = (float)b0[d];
                acc[0][d] += w0.x * xf; acc[1][d] += w0.y * xf;
                acc[2][d] += w0.z * xf; acc[3][d] += w0.w * xf;
            }
            z[0] += w0.x; z[1] += w0.y; z[2] += w0.z; z[3] += w0.w;
        }
        // normalize: hi plane -> LDS, lo plane -> lvk registers (acc DIES here)
#pragma unroll
        for (int h = 0; h < HEADS; h++) {
            const float inv = 1.f / z[h];
            bf16x8 hv, lv;
#pragma unroll
            for (int d = 0; d < 8; d++) {
                const float v = acc[h][d] * inv;
                const __bf16 hh = (__bf16)v;
                hv[d] = hh;
                lv[d] = (__bf16)(v - (float)hh);
            }
            *(bf16x8*)&ax[ln * AXS + h * IN_DIM + d8] = hv;
            lvk[h] = lv;
        }
    }
    __syncthreads();

    // ---- phase 1a: preload hi A-fragments ----
    bf16x8 ahv[4];
    const int abase = l16 * AXS + wave * IN_DIM;
#pragma unroll
    for (int kk = 0; kk < 4; kk++)
        ahv[kk] = *(const bf16x8*)&ax[abase + kk * 32 + quad * 8];
    __syncthreads();   // all hi reads done -> plane reusable

    // ---- lo plane from registers -> LDS ----
#pragma unroll
    for (int h = 0; h < HEADS; h++)
        *(bf16x8*)&ax[ln * AXS + h * IN_DIM + d8] = lvk[h];
    __syncthreads();

    bf16x8 alv[4];
#pragma unroll
    for (int kk = 0; kk < 4; kk++)
        alv[kk] = *(const bf16x8*)&ax[abase + kk * 32 + quad * 8];
    __syncthreads();   // all lo reads done -> uni free for smh/sml

    // ---- phase 1b: MFMA + ELU write into the aliased smh/sml region ----
    {
        f32x4 acc1[4];
#pragma unroll
        for (int t = 0; t < 4; t++) acc1[t] = (f32x4){0.f, 0.f, 0.f, 0.f};
#pragma unroll
        for (int kk = 0; kk < 4; kk++) {
#pragma unroll
            for (int t = 0; t < 4; t++) {
                const size_t bi = (size_t)wave * W1_FRAG +
                                  ((size_t)(t * 4 + kk) * 64 + lane) * 8;
                bf16x8 bhv = *(const bf16x8*)&B1h[bi];
                bf16x8 blv = *(const bf16x8*)&B1l[bi];
                acc1[t] = __builtin_amdgcn_mfma_f32_16x16x32_bf16(ahv[kk], bhv, acc1[t], 0, 0, 0);
                acc1[t] = __builtin_amdgcn_mfma_f32_16x16x32_bf16(alv[kk], bhv, acc1[t], 0, 0, 0);
                acc1[t] = __builtin_amdgcn_mfma_f32_16x16x32_bf16(ahv[kk], blv, acc1[t], 0, 0, 0);
            }
        }
        // ELU(+b1) -> aliased LDS hi/lo planes
#pragma unroll
        for (int t = 0; t < 4; t++) {
            const int c = wave * 64 + t * 16 + l16;
            const float bb = b1[c];
#pragma unroll
            for (int r = 0; r < 4; r++) {
                const float v = eluf(acc1[t][r] + bb);
                const __bf16 hh = (__bf16)v;
                smh[(quad * 4 + r) * LDSB + c] = hh;
                sml[(quad * 4 + r) * LDSB + c] = (__bf16)(v - (float)hh);
            }
        }
    }
    __syncthreads();

    // ---- phase 2: this wave's output cols = tiles {2*wave, 2*wave+1} ----
    f32x4 acc2[2];
#pragma unroll
    for (int t = 0; t < 2; t++) acc2[t] = (f32x4){0.f, 0.f, 0.f, 0.f};
    const int arow = l16 * LDSB;
#pragma unroll
    for (int kk = 0; kk < 8; kk++) {
        const int k0 = kk * 32 + quad * 8;
        bf16x8 ah = *(const bf16x8*)&smh[arow + k0];
        bf16x8 al = *(const bf16x8*)&sml[arow + k0];
#pragma unroll
        for (int tt = 0; tt < 2; tt++) {
            const int t = wave * 2 + tt;
            const size_t bi = ((size_t)(t * 8 + kk) * 64 + lane) * 8;
            bf16x8 bhv = *(const bf16x8*)&B2h[bi];
            bf16x8 blv = *(const bf16x8*)&B2l[bi];
            acc2[tt] = __builtin_amdgcn_mfma_f32_16x16x32_bf16(ah, bhv, acc2[tt], 0, 0, 0);
            acc2[tt] = __builtin_amdgcn_mfma_f32_16x16x32_bf16(al, bhv, acc2[tt], 0, 0, 0);
            acc2[tt] = __builtin_amdgcn_mfma_f32_16x16x32_bf16(ah, blv, acc2[tt], 0, 0, 0);
        }
    }

    // store g2 (bf16) + alpha2 logit partials (f32, exact from acc2)
    const int rowS = row0 + quad * 4;
#pragma unroll
    for (int tt = 0; tt < 2; tt++) {
        const int t = wave * 2 + tt;
#pragma unroll
        for (int r = 0; r < 4; r++) {
            const int rr = rowS + r;
            if (rr < M) g2b[(size_t)rr * EMB + t * 16 + l16] = (__bf16)acc2[tt][r];
        }
    }
#pragma unroll
    for (int r = 0; r < 4; r++) {
        float ps = 0.f, pd = 0.f;
#pragma unroll
        for (int tt = 0; tt < 2; tt++) {
            const int c = (wave * 2 + tt) * 16 + l16;
            ps += acc2[tt][r] * avs[c];
            pd += acc2[tt][r] * avd[c];
        }
#pragma unroll
        for (int o = 1; o < 16; o <<= 1) {
            ps += __shfl_xor(ps, o);
            pd += __shfl_xor(pd, o);
        }
        if (l16 == 0) {
            pps[wave][quad * 4 + r] = ps;
            pdd[wave][quad * 4 + r] = pd;
        }
    }
    __syncthreads();
    if (tid < 16) {
        const int rr = row0 + tid;
        if (rr < M) {
            as_out[rr] = pps[0][tid] + pps[1][tid] + pps[2][tid] + pps[3][tid];
            ad_out[rr] = pdd[0][tid] + pdd[1][tid] + pdd[2][tid] + pdd[3][tid];
        }
    }
}

// ---------------------------------------------------------------------------
// Layer-2 aggregation (r6-proven layout, bf16 out2, u16 col).
// ---------------------------------------------------------------------------
__global__ __launch_bounds__(256) void agg2_kernel(const int* __restrict__ off,
                                                   const int* __restrict__ offE,
                                                   const unsigned short* __restrict__ col,
                                                   const float* __restrict__ as2,
                                                   const float* __restrict__ ad2,
                                                   const __bf16* __restrict__ g2b,
                                                   __bf16* __restrict__ out2, int N) {
    const int w  = blockIdx.x * 16 + (threadIdx.x >> 4);   // exact fit
    const int d8 = (threadIdx.x & 15) * 8;
    const float ad2w = ad2[w];
    f32x2 acc[4];
    float z;
    {   // self-loop
        const float wt = __expf(lrelu(as2[w] + ad2w));
        const bf16x8 hv = *(const bf16x8*)&g2b[(size_t)w * EMB + d8];
#pragma unroll
        for (int p = 0; p < 4; p++) {
            const f32x2 xf = {(float)hv[2 * p], (float)hv[2 * p + 1]};
            acc[p] = s2(wt) * xf;
        }
        z = wt;
    }
    const int jb = off[w], je = offE[w];
    int j = jb;
    for (; j + 3 < je; j += 4) {
        int s[4];
#pragma unroll
        for (int u = 0; u < 4; u++) s[u] = (int)col[j + u];
        float av[4];
#pragma unroll
        for (int u = 0; u < 4; u++) av[u] = as2[s[u]];
        bf16x8 bv[4];
#pragma unroll
        for (int u = 0; u < 4; u++)
            bv[u] = *(const bf16x8*)&g2b[(size_t)s[u] * EMB + d8];
#pragma unroll
        for (int u = 0; u < 4; u++) {
            const float wt = __expf(lrelu(av[u] + ad2w));
#pragma unroll
            for (int p = 0; p < 4; p++) {
                const f32x2 xf = {(float)bv[u][2 * p], (float)bv[u][2 * p + 1]};
                acc[p] += s2(wt) * xf;
            }
            z += wt;
        }
    }
    for (; j < je; j++) {
        const int s0 = (int)col[j];
        const float wt = __expf(lrelu(as2[s0] + ad2w));
        const bf16x8 b0 = *(const bf16x8*)&g2b[(size_t)s0 * EMB + d8];
#pragma unroll
        for (int p = 0; p < 4; p++) {
            const f32x2 xf = {(float)b0[2 * p], (float)b0[2 * p + 1]};
            acc[p] += s2(wt) * xf;
        }
        z += wt;
    }
    const float inv = 1.f / z;
    bf16x8 ov;
#pragma unroll
    for (int p = 0; p < 4; p++) {
        ov[2 * p]     = (__bf16)(acc[p][0] * inv);
        ov[2 * p + 1] = (__bf16)(acc[p][1] * inv);
    }
    *(bf16x8*)&out2[(size_t)w * EMB + d8] = ov;
}

// ---------------------------------------------------------------------------
// Global mean pool (run-length form, bf16 out2 input) + divide.
// ---------------------------------------------------------------------------
__global__ __launch_bounds__(128) void pool_kernel(const __bf16* __restrict__ out2,
                                                   const float* __restrict__ b2,
                                                   const int* __restrict__ batch,
                                                   float* __restrict__ pool,
                                                   float* __restrict__ cnt, int N) {
    const int c = threadIdx.x;
    const int n0 = blockIdx.x * 64;
    const int nend = min(n0 + 64, N);
    const float bias = b2[c];
    float acc = 0.f, cacc = 0.f;
    int curg = batch[n0];
    for (int n = n0; n < nend; n++) {
        const int g = batch[n];
        if (g != curg) {
            atomicAdd(&pool[curg * EMB + c], acc);
            if (c == 0) atomicAdd(&cnt[curg], cacc);
            acc = 0.f; cacc = 0.f; curg = g;
        }
        float v = (float)out2[(size_t)n * EMB + c] + bias;
        v = v > 0.f ? v : expm1f(v);
        acc += v;
        cacc += 1.f;
    }
    atomicAdd(&pool[curg * EMB + c], acc);
    if (c == 0) atomicAdd(&cnt[curg], cacc);
}

__global__ __launch_bounds__(256) void div_kernel(const float* __restrict__ pool,
                                                  const float* __restrict__ cnt,
                                                  float* __restrict__ out) {
    const int i = blockIdx.x * 256 + threadIdx.x;
    out[i] = pool[i] / fmaxf(cnt[i >> 7], 1.f);
}

// ---------------------------------------------------------------------------
extern "C" void kernel_launch(void* const* d_in, const int* in_sizes, int n_in,
                              void* d_out, int out_size, void* d_ws, size_t ws_size,
                              hipStream_t stream) {
    const float* x      = (const float*)d_in[0];
    const int*   ei     = (const int*)d_in[1];
    const int*   batch  = (const int*)d_in[3];
    const float* W1     = (const float*)d_in[4];
    const float* a_src1 = (const float*)d_in[5];
    const float* a_dst1 = (const float*)d_in[6];
    const float* b1     = (const float*)d_in[7];
    const float* W2     = (const float*)d_in[8];
    const float* a_src2 = (const float*)d_in[9];
    const float* a_dst2 = (const float*)d_in[10];
    const float* b2     = (const float*)d_in[11];
    float* out = (float*)d_out;

    const int N = N_NODES, E = N_EDGES;

    size_t cur_off = 0;
    auto carve = [&](size_t bytes) {
        size_t o = cur_off;
        cur_off = (cur_off + bytes + 255) & ~(size_t)255;
        return (char*)d_ws + o;
    };
    // zero-init region: pool + cnt + bcnt
    float* pool  = (float*)carve((size_t)N_GRAPHS * EMB * 4);
    float* cnt   = (float*)carve((size_t)N_GRAPHS * 4);
    int* bcnt    = (int*)carve((size_t)NBUCK * 4);
    const size_t zero_bytes = cur_off;
    int* gbase   = (int*)carve((size_t)(NBUCK + 1) * 4);
    int* gcur    = (int*)carve((size_t)NBUCK * 4);
    unsigned* stage = (unsigned*)carve((size_t)E * 4);
    float* wst   = (float*)carve((size_t)8 * IN_DIM * 4);
    __bf16* B1h  = (__bf16*)carve((size_t)HEADS * W1_FRAG * 2);
    __bf16* B1l  = (__bf16*)carve((size_t)HEADS * W1_FRAG * 2);
    __bf16* B2h  = (__bf16*)carve((size_t)F1 * EMB * 2);
    __bf16* B2l  = (__bf16*)carve((size_t)F1 * EMB * 2);
    __bf16* xb   = (__bf16*)carve((size_t)N * IN_DIM * 2);
    int* off     = (int*)carve((size_t)N * 4);
    int* offE    = (int*)carve((size_t)N * 4);
    unsigned short* col = (unsigned short*)carve((size_t)E * 2);
    float4* w4   = (float4*)carve((size_t)E * 16);
    __bf16* g2b  = (__bf16*)carve((size_t)N * EMB * 2);
    __bf16* out2 = (__bf16*)carve((size_t)N * EMB * 2);
    float* as1   = (float*)carve((size_t)N * HEADS * 4);
    float* ad1   = (float*)carve((size_t)N * HEADS * 4);
    float* as2   = (float*)carve((size_t)N * 4);
    float* ad2   = (float*)carve((size_t)N * 4);

    hipMemsetAsync(d_ws, 0, zero_bytes, stream);

    // prep: bucket histogram + weight packs + wst
    prep_kernel<<<P1_BLOCKS + 36, 256, 0, stream>>>(
        ei, bcnt, W1, B1h, B1l, W2, B2h, B2l, a_src1, a_dst1, wst);

    // 196-entry bucket scan
    scan196_kernel<<<1, 256, 0, stream>>>(bcnt, gbase, gcur);

    // rank-8 logit projection + xb emit + single-pass bucketed append
    proj_append_kernel<<<AS_BLOCKS + P1_BLOCKS, 256, 0, stream>>>(
        x, wst, as1, ad1, xb, ei, gcur, stage);

    // per-bucket CSR build (off/offE) + col(u16)/w4 placement via LDS cursors
    distribute_kernel<<<NBUCK, 256, 0, stream>>>(stage, gbase, as1, ad1,
                                                 off, offE, col, w4, N);

    // fused: gather-aggregate -> (@W1 -> ELU -> @W2) + alpha2 (6 blocks/CU)
    agg_gemm12_kernel<<<AGG12_BLOCKS, 256, 0, stream>>>(off, offE, col, w4, xb,
                                                        as1, ad1, B1h, B1l, b1,
                                                        B2h, B2l, a_src2, a_dst2,
                                                        g2b, as2, ad2, N);

    // layer-2 aggregation (bf16 out2), then run-length pool + divide
    agg2_kernel<<<AGG12_BLOCKS, 256, 0, stream>>>(off, offE, col, as2, ad2,
                                                  g2b, out2, N);

    pool_kernel<<<(N + 63) / 64, 128, 0, stream>>>(out2, b2, batch, pool, cnt, N);
    div_kernel<<<(N_GRAPHS * EMB) / 256, 256, 0, stream>>>(pool, cnt, out);
}

// Round 15
// 275.792 us; speedup vs baseline: 1.1154x; 1.1154x over previous
//
#include <hip/hip_runtime.h>
#include <hip/hip_bf16.h>
#include <cstddef>

// Problem constants (fixed-shape problem)
constexpr int N_NODES = 50000;
constexpr int N_EDGES = 800000;
constexpr int IN_DIM  = 128;
constexpr int HID     = 64;
constexpr int HEADS   = 4;
constexpr int F1      = HEADS * HID;  // 256
constexpr int EMB     = 128;
constexpr int N_GRAPHS = 64;

// per-head W1 fragment size (NT=4, KK=4): 4*4*64*8 bf16 elements
constexpr int W1_FRAG = 4 * 4 * 64 * 8;                      // 8192
// gemm12 LDS tile stride in bf16 elems: 264*2 = 528 B rows (16 B aligned for
// ds_read_b128; 132 dwords mod 32 = 4 -> ~2-way bank alias, free per m136)
constexpr int LDSB = 264;
// fused-aggregate LDS node-row stride: 4*128+8 elems = 1040 B (16 B aligned,
// 260 dwords mod 32 = 4 -> same mild alias class as LDSB)
constexpr int AXS  = HEADS * IN_DIM + 8;                     // 520
// bucketed CSR build: bucket regions allocated in arbitrary order (196-entry
// scan), off/offE computed per-bucket in LDS (r10 structure).
constexpr int NBUCK    = (N_NODES + 255) / 256;              // 196
constexpr int P1_CHUNK = 2048;                               // edges per hist/append block
constexpr int P1_BLOCKS = (N_EDGES + P1_CHUNK - 1) / P1_CHUNK; // 391
constexpr int AS_BLOCKS = N_NODES / 16;                      // 3125 (exact)
constexpr int AGG12_BLOCKS = N_NODES / 16;                   // 3125 (exact)
static_assert(N_NODES % 16 == 0, "16-row tiling assumes exact fit");
static_assert(N_NODES <= 65536, "u16 col requires node ids < 65536");
static_assert(16 * AXS <= 2 * 16 * LDSB, "ax plane must fit the uni buffer");

typedef __bf16 bf16x8 __attribute__((ext_vector_type(8)));
typedef __bf16 bf16x2 __attribute__((ext_vector_type(2)));
typedef float  f32x4  __attribute__((ext_vector_type(4)));
typedef float  f32x2  __attribute__((ext_vector_type(2)));

__device__ __forceinline__ float lrelu(float x) { return x > 0.f ? x : 0.2f * x; }
__device__ __forceinline__ float eluf(float x)  { return x > 0.f ? x : expm1f(x); }
__device__ __forceinline__ f32x2 s2(float s)    { return (f32x2){s, s}; }

// ---------------------------------------------------------------------------
// Pack a [K x 16*NT] submatrix of B (leading dim ld, origin col0) into
// per-lane MFMA B-fragments, split hi/lo bf16.
// ---------------------------------------------------------------------------
__device__ __forceinline__ void pack_frag(const float* __restrict__ B,
                                          __bf16* __restrict__ hi,
                                          __bf16* __restrict__ lo,
                                          int pblk, int NT, int KK, int ld, int col0) {
    const int gid = pblk * 256 + threadIdx.x;
    if (gid >= NT * KK * 64) return;
    const int lane = gid & 63;
    const int rem  = gid >> 6;
    const int kk   = rem % KK;
    const int t    = rem / KK;
    const int n    = col0 + t * 16 + (lane & 15);
    const int k0   = kk * 32 + (lane >> 4) * 8;
#pragma unroll
    for (int j = 0; j < 8; j++) {
        const float v = B[(size_t)(k0 + j) * ld + n];
        const __bf16 h = (__bf16)v;
        hi[(size_t)gid * 8 + j] = h;
        lo[(size_t)gid * 8 + j] = (__bf16)(v - (float)h);
    }
}

// ---------------------------------------------------------------------------
// prep: [bucket histogram (196 buckets, LDS-staged) | pack W1 | pack W2 |
// wst = W1^T·a per head].
// ---------------------------------------------------------------------------
__global__ __launch_bounds__(256) void prep_kernel(const int* __restrict__ ei,
                                                   int* __restrict__ bcnt,
                                                   const float* __restrict__ W1,
                                                   __bf16* __restrict__ B1h,
                                                   __bf16* __restrict__ B1l,
                                                   const float* __restrict__ W2,
                                                   __bf16* __restrict__ B2h,
                                                   __bf16* __restrict__ B2l,
                                                   const float* __restrict__ as1v,
                                                   const float* __restrict__ ad1v,
                                                   float* __restrict__ wst) {
    const int b = blockIdx.x;
    if (b < P1_BLOCKS) {
        __shared__ int lh[NBUCK];
        const int tid = threadIdx.x;
        for (int i = tid; i < NBUCK; i += 256) lh[i] = 0;
        __syncthreads();
        const int e0 = b * P1_CHUNK;
#pragma unroll
        for (int i = 0; i < P1_CHUNK / 256; i++) {
            const int e = e0 + i * 256 + tid;
            if (e < N_EDGES) atomicAdd(&lh[ei[N_EDGES + e] >> 8], 1);
        }
        __syncthreads();
        for (int i = tid; i < NBUCK; i += 256) {
            const int c = lh[i];
            if (c) atomicAdd(&bcnt[i], c);
        }
        return;
    }
    const int pb = b - P1_BLOCKS;
    if (pb < 16) {
        const int head = pb >> 2;
        pack_frag(W1, B1h + head * W1_FRAG, B1l + head * W1_FRAG,
                  pb & 3, 4, 4, F1, head * HID);
        return;
    }
    if (pb < 32) {
        pack_frag(W2, B2h, B2l, pb - 16, 8, 8, EMB, 0);
        return;
    }
    // wst[o][c] = sum_k W1[c][h*64+k] * a[h][k], o = (src?0:4)+h
    const int gid = (pb - 32) * 256 + threadIdx.x;  // 0..1023
    const int o = gid >> 7, c = gid & 127;
    const int h = o & 3;
    const float* av = (o < 4) ? as1v : ad1v;
    float s = 0.f;
#pragma unroll 8
    for (int k = 0; k < HID; k++)
        s += W1[(size_t)c * F1 + h * HID + k] * av[h * HID + k];
    wst[o * IN_DIM + c] = s;
}

// ---------------------------------------------------------------------------
// scan196: single-block exclusive scan over bucket counts -> gbase[197],
// seeds the append cursors gcur.
// ---------------------------------------------------------------------------
__global__ __launch_bounds__(256) void scan196_kernel(const int* __restrict__ bcnt,
                                                      int* __restrict__ gbase,
                                                      int* __restrict__ gcur) {
    __shared__ int sm[256];
    const int t = threadIdx.x;
    const int v = (t < NBUCK) ? bcnt[t] : 0;
    sm[t] = v;
    __syncthreads();
    int val = v;
#pragma unroll
    for (int o = 1; o < 256; o <<= 1) {
        const int add = (t >= o) ? sm[t - o] : 0;
        __syncthreads();
        val += add;
        sm[t] = val;
        __syncthreads();
    }
    if (t < NBUCK) { gbase[t] = val - v; gcur[t] = val - v; }
    if (t == NBUCK - 1) gbase[NBUCK] = val;
}

// ---------------------------------------------------------------------------
// proj_append: [rank-8 logit projection + x->bf16 emit | SINGLE-PASS bucketed
// edge append].
// ---------------------------------------------------------------------------
__global__ __launch_bounds__(256) void proj_append_kernel(
        const float* __restrict__ x, const float* __restrict__ wst,
        float* __restrict__ as_out, float* __restrict__ ad_out,
        __bf16* __restrict__ xb,
        const int* __restrict__ ei, int* __restrict__ gcur,
        unsigned* __restrict__ stage) {
    const int tid = threadIdx.x;
    if (blockIdx.x < AS_BLOCKS) {
        const int n   = blockIdx.x * 16 + (tid >> 4);
        const int l16 = tid & 15;
        const int d8  = l16 * 8;
        const float4 xa = *(const float4*)&x[(size_t)n * IN_DIM + d8];
        const float4 xc = *(const float4*)&x[(size_t)n * IN_DIM + d8 + 4];
        bf16x8 bw;
        bw[0] = (__bf16)xa.x; bw[1] = (__bf16)xa.y;
        bw[2] = (__bf16)xa.z; bw[3] = (__bf16)xa.w;
        bw[4] = (__bf16)xc.x; bw[5] = (__bf16)xc.y;
        bw[6] = (__bf16)xc.z; bw[7] = (__bf16)xc.w;
        *(bf16x8*)&xb[(size_t)n * IN_DIM + d8] = bw;
        float p[8];
#pragma unroll
        for (int o = 0; o < 8; o++) {
            const float4 wa = *(const float4*)&wst[o * IN_DIM + d8];
            const float4 wb = *(const float4*)&wst[o * IN_DIM + d8 + 4];
            p[o] = xa.x * wa.x + xa.y * wa.y + xa.z * wa.z + xa.w * wa.w
                 + xc.x * wb.x + xc.y * wb.y + xc.z * wb.z + xc.w * wb.w;
        }
#pragma unroll
        for (int off = 1; off < 16; off <<= 1) {
#pragma unroll
            for (int o = 0; o < 8; o++) p[o] += __shfl_xor(p[o], off);
        }
        if (l16 == 0) {
            *(float4*)&as_out[n * HEADS] = (float4){p[0], p[1], p[2], p[3]};
            *(float4*)&ad_out[n * HEADS] = (float4){p[4], p[5], p[6], p[7]};
        }
        return;
    }
    // single-pass bucketed append
    __shared__ int lhist[NBUCK];
    __shared__ int lbase[NBUCK];
    const int e0 = (blockIdx.x - AS_BLOCKS) * P1_CHUNK;
    for (int b = tid; b < NBUCK; b += 256) lhist[b] = 0;
    __syncthreads();
    unsigned pv[P1_CHUNK / 256];
    int      bk[P1_CHUNK / 256];
    int      rk[P1_CHUNK / 256];
#pragma unroll
    for (int i = 0; i < P1_CHUNK / 256; i++) {
        const int e = e0 + i * 256 + tid;
        if (e < N_EDGES) {
            const int s = ei[e], d = ei[N_EDGES + e];
            pv[i] = (unsigned)s | ((unsigned)d << 16);
            bk[i] = d >> 8;
            rk[i] = atomicAdd(&lhist[bk[i]], 1);
        } else {
            bk[i] = -1;
        }
    }
    __syncthreads();
    for (int b = tid; b < NBUCK; b += 256) {
        const int c = lhist[b];
        lbase[b] = c ? atomicAdd(&gcur[b], c) : 0;
    }
    __syncthreads();
#pragma unroll
    for (int i = 0; i < P1_CHUNK / 256; i++) {
        if (bk[i] >= 0) stage[lbase[bk[i]] + rk[i]] = pv[i];
    }
}

// ---------------------------------------------------------------------------
// distribute: one block per bucket. LDS node histogram + block scan ->
// off/offE; place col (u16) + w4 using LDS cursors.
// ---------------------------------------------------------------------------
__global__ __launch_bounds__(256) void distribute_kernel(
        const unsigned* __restrict__ stage, const int* __restrict__ gbase,
        const float* __restrict__ as1, const float* __restrict__ ad1,
        int* __restrict__ off, int* __restrict__ offE,
        unsigned short* __restrict__ col, float4* __restrict__ w4, int N) {
    __shared__ int lcnt[256];
    __shared__ int sm[256];
    __shared__ int lcur[256];
    const int t = threadIdx.x;
    const int b = blockIdx.x;
    const int wb = gbase[b], we = gbase[b + 1];
    lcnt[t] = 0;
    __syncthreads();
    for (int j = wb + t; j < we; j += 256)
        atomicAdd(&lcnt[(stage[j] >> 16) & 255], 1);
    __syncthreads();
    const int v = lcnt[t];
    sm[t] = v;
    __syncthreads();
    int val = v;
#pragma unroll
    for (int o = 1; o < 256; o <<= 1) {
        const int add = (t >= o) ? sm[t - o] : 0;
        __syncthreads();
        val += add;
        sm[t] = val;
        __syncthreads();
    }
    const int node = b * 256 + t;
    if (node < N) {
        off[node]  = wb + val - v;
        offE[node] = wb + val;
    }
    lcur[t] = wb + val - v;
    __syncthreads();
    for (int j = wb + t; j < we; j += 256) {
        const unsigned p = stage[j];
        const int s = (int)(p & 0xFFFFu);
        const int d = (int)(p >> 16);
        const int pos = atomicAdd(&lcur[d & 255], 1);
        const float4 a  = *(const float4*)&as1[s * HEADS];
        const float4 bb = *(const float4*)&ad1[d * HEADS];
        float4 o;
        o.x = __expf(lrelu(a.x + bb.x));
        o.y = __expf(lrelu(a.y + bb.y));
        o.z = __expf(lrelu(a.z + bb.z));
        o.w = __expf(lrelu(a.w + bb.w));
        col[pos] = (unsigned short)s;
        w4[pos] = o;
    }
}

// ---------------------------------------------------------------------------
// FUSED layer-1 aggregation + layer-1 GEMM + layer-2 GEMM, 16 rows/block.
// LDS diet (17.4 KB, sequential hi/lo staging, lo cached in bf16 regs) with
// the PROVEN-SAFE launch bound (256,4): VGPR cap 128 >> natural ~70, so no
// spill is possible (r11 precedent); occupancy now set by the HW limits —
// LDS allows 9 blocks/CU, VGPR allows 512/alloc waves/SIMD — instead of the
// min_waves>=6 allocator policy that self-limited to 32-40 VGPR and spilled
// 91-428 MB in r12-r14.
// ---------------------------------------------------------------------------
__global__ __launch_bounds__(256, 4) void agg_gemm12_kernel(
        const int* __restrict__ off, const int* __restrict__ offE,
        const unsigned short* __restrict__ col,
        const float4* __restrict__ w4, const __bf16* __restrict__ xb,
        const float* __restrict__ as1, const float* __restrict__ ad1,
        const __bf16* __restrict__ B1h, const __bf16* __restrict__ B1l,
        const float* __restrict__ b1,
        const __bf16* __restrict__ B2h, const __bf16* __restrict__ B2l,
        const float* __restrict__ avs, const float* __restrict__ avd,
        __bf16* __restrict__ g2b, float* __restrict__ as_out,
        float* __restrict__ ad_out, int M) {
    __shared__ __bf16 uni[2 * 16 * LDSB];    // 16,896 B (ax plane: 16,640 B)
    __shared__ float pps[4][16], pdd[4][16];
    __bf16* const ax  = uni;                 // [16][AXS] single hi/lo plane
    __bf16* const smh = uni;                 // [16][LDSB]
    __bf16* const sml = uni + 16 * LDSB;     // [16][LDSB]
    const int tid  = threadIdx.x;
    const int wave = tid >> 6, lane = tid & 63;
    const int quad = lane >> 4, l16 = lane & 15;
    const int row0 = blockIdx.x * 16;
    const int ln = wave * 4 + quad;          // local node 0..15
    const int w  = row0 + ln;                // global node (exact fit)
    const int d8 = l16 * 8;                  // this lane's 8 dims

    // ---- phase 0: gather-aggregate; one node per 16-lane group ----
    bf16x8 lvk[HEADS];                       // lo plane cache (16 VGPR)
    {
        float acc[HEADS][8];
        float z[HEADS];
        {   // self-loop
            const float4 asv = *(const float4*)&as1[w * HEADS];
            const float4 adv = *(const float4*)&ad1[w * HEADS];
            const float ws0 = __expf(lrelu(asv.x + adv.x));
            const float ws1 = __expf(lrelu(asv.y + adv.y));
            const float ws2 = __expf(lrelu(asv.z + adv.z));
            const float ws3 = __expf(lrelu(asv.w + adv.w));
            const bf16x8 xv = *(const bf16x8*)&xb[(size_t)w * IN_DIM + d8];
#pragma unroll
            for (int d = 0; d < 8; d++) {
                const float xf = (float)xv[d];
                acc[0][d] = ws0 * xf; acc[1][d] = ws1 * xf;
                acc[2][d] = ws2 * xf; acc[3][d] = ws3 * xf;
            }
            z[0] = ws0; z[1] = ws1; z[2] = ws2; z[3] = ws3;
        }
        const int jb = off[w], je = offE[w];
        int j = jb;
        for (; j + 3 < je; j += 4) {
            int    s[4];
            float4 ww[4];
            bf16x8 bv[4];
#pragma unroll
            for (int u = 0; u < 4; u++) s[u] = (int)col[j + u];
#pragma unroll
            for (int u = 0; u < 4; u++) ww[u] = w4[j + u];
#pragma unroll
            for (int u = 0; u < 4; u++)
                bv[u] = *(const bf16x8*)&xb[(size_t)s[u] * IN_DIM + d8];
#pragma unroll
            for (int u = 0; u < 4; u++) {
#pragma unroll
                for (int d = 0; d < 8; d++) {
                    const float xf = (float)bv[u][d];
                    acc[0][d] += ww[u].x * xf;
                    acc[1][d] += ww[u].y * xf;
                    acc[2][d] += ww[u].z * xf;
                    acc[3][d] += ww[u].w * xf;
                }
                z[0] += ww[u].x; z[1] += ww[u].y;
                z[2] += ww[u].z; z[3] += ww[u].w;
            }
        }
        for (; j < je; j++) {
            const int s0 = (int)col[j];
            const float4 w0 = w4[j];
            const bf16x8 b0 = *(const bf16x8*)&xb[(size_t)s0 * IN_DIM + d8];
#pragma unroll
            for (int d = 0; d < 8; d++) {
                const float xf = (float)b0[d];
                acc[0][d] += w0.x * xf; acc[1][d] += w0.y * xf;
                acc[2][d] += w0.z * xf; acc[3][d] += w0.w * xf;
            }
            z[0] += w0.x; z[1] += w0.y; z[2] += w0.z; z[3] += w0.w;
        }
        // normalize: hi plane -> LDS, lo plane -> lvk registers (acc DIES here)
#pragma unroll
        for (int h = 0; h < HEADS; h++) {
            const float inv = 1.f / z[h];
            bf16x8 hv, lv;
#pragma unroll
            for (int d = 0; d < 8; d++) {
                const float v = acc[h][d] * inv;
                const __bf16 hh = (__bf16)v;
                hv[d] = hh;
                lv[d] = (__bf16)(v - (float)hh);
            }
            *(bf16x8*)&ax[ln * AXS + h * IN_DIM + d8] = hv;
            lvk[h] = lv;
        }
    }
    __syncthreads();

    // ---- phase 1a: preload hi A-fragments ----
    bf16x8 ahv[4];
    const int abase = l16 * AXS + wave * IN_DIM;
#pragma unroll
    for (int kk = 0; kk < 4; kk++)
        ahv[kk] = *(const bf16x8*)&ax[abase + kk * 32 + quad * 8];
    __syncthreads();   // all hi reads done -> plane reusable

    // ---- lo plane from registers -> LDS ----
#pragma unroll
    for (int h = 0; h < HEADS; h++)
        *(bf16x8*)&ax[ln * AXS + h * IN_DIM + d8] = lvk[h];
    __syncthreads();

    bf16x8 alv[4];
#pragma unroll
    for (int kk = 0; kk < 4; kk++)
        alv[kk] = *(const bf16x8*)&ax[abase + kk * 32 + quad * 8];
    __syncthreads();   // all lo reads done -> uni free for smh/sml

    // ---- phase 1b: MFMA + ELU write into the aliased smh/sml region ----
    {
        f32x4 acc1[4];
#pragma unroll
        for (int t = 0; t < 4; t++) acc1[t] = (f32x4){0.f, 0.f, 0.f, 0.f};
#pragma unroll
        for (int kk = 0; kk < 4; kk++) {
#pragma unroll
            for (int t = 0; t < 4; t++) {
                const size_t bi = (size_t)wave * W1_FRAG +
                                  ((size_t)(t * 4 + kk) * 64 + lane) * 8;
                bf16x8 bhv = *(const bf16x8*)&B1h[bi];
                bf16x8 blv = *(const bf16x8*)&B1l[bi];
                acc1[t] = __builtin_amdgcn_mfma_f32_16x16x32_bf16(ahv[kk], bhv, acc1[t], 0, 0, 0);
                acc1[t] = __builtin_amdgcn_mfma_f32_16x16x32_bf16(alv[kk], bhv, acc1[t], 0, 0, 0);
                acc1[t] = __builtin_amdgcn_mfma_f32_16x16x32_bf16(ahv[kk], blv, acc1[t], 0, 0, 0);
            }
        }
        // ELU(+b1) -> aliased LDS hi/lo planes
#pragma unroll
        for (int t = 0; t < 4; t++) {
            const int c = wave * 64 + t * 16 + l16;
            const float bb = b1[c];
#pragma unroll
            for (int r = 0; r < 4; r++) {
                const float v = eluf(acc1[t][r] + bb);
                const __bf16 hh = (__bf16)v;
                smh[(quad * 4 + r) * LDSB + c] = hh;
                sml[(quad * 4 + r) * LDSB + c] = (__bf16)(v - (float)hh);
            }
        }
    }
    __syncthreads();

    // ---- phase 2: this wave's output cols = tiles {2*wave, 2*wave+1} ----
    f32x4 acc2[2];
#pragma unroll
    for (int t = 0; t < 2; t++) acc2[t] = (f32x4){0.f, 0.f, 0.f, 0.f};
    const int arow = l16 * LDSB;
#pragma unroll
    for (int kk = 0; kk < 8; kk++) {
        const int k0 = kk * 32 + quad * 8;
        bf16x8 ah = *(const bf16x8*)&smh[arow + k0];
        bf16x8 al = *(const bf16x8*)&sml[arow + k0];
#pragma unroll
        for (int tt = 0; tt < 2; tt++) {
            const int t = wave * 2 + tt;
            const size_t bi = ((size_t)(t * 8 + kk) * 64 + lane) * 8;
            bf16x8 bhv = *(const bf16x8*)&B2h[bi];
            bf16x8 blv = *(const bf16x8*)&B2l[bi];
            acc2[tt] = __builtin_amdgcn_mfma_f32_16x16x32_bf16(ah, bhv, acc2[tt], 0, 0, 0);
            acc2[tt] = __builtin_amdgcn_mfma_f32_16x16x32_bf16(al, bhv, acc2[tt], 0, 0, 0);
            acc2[tt] = __builtin_amdgcn_mfma_f32_16x16x32_bf16(ah, blv, acc2[tt], 0, 0, 0);
        }
    }

    // store g2 (bf16) + alpha2 logit partials (f32, exact from acc2)
    const int rowS = row0 + quad * 4;
#pragma unroll
    for (int tt = 0; tt < 2; tt++) {
        const int t = wave * 2 + tt;
#pragma unroll
        for (int r = 0; r < 4; r++) {
            const int rr = rowS + r;
            if (rr < M) g2b[(size_t)rr * EMB + t * 16 + l16] = (__bf16)acc2[tt][r];
        }
    }
#pragma unroll
    for (int r = 0; r < 4; r++) {
        float ps = 0.f, pd = 0.f;
#pragma unroll
        for (int tt = 0; tt < 2; tt++) {
            const int c = (wave * 2 + tt) * 16 + l16;
            ps += acc2[tt][r] * avs[c];
            pd += acc2[tt][r] * avd[c];
        }
#pragma unroll
        for (int o = 1; o < 16; o <<= 1) {
            ps += __shfl_xor(ps, o);
            pd += __shfl_xor(pd, o);
        }
        if (l16 == 0) {
            pps[wave][quad * 4 + r] = ps;
            pdd[wave][quad * 4 + r] = pd;
        }
    }
    __syncthreads();
    if (tid < 16) {
        const int rr = row0 + tid;
        if (rr < M) {
            as_out[rr] = pps[0][tid] + pps[1][tid] + pps[2][tid] + pps[3][tid];
            ad_out[rr] = pdd[0][tid] + pdd[1][tid] + pdd[2][tid] + pdd[3][tid];
        }
    }
}

// ---------------------------------------------------------------------------
// Layer-2 aggregation (r6-proven layout, bf16 out2, u16 col).
// ---------------------------------------------------------------------------
__global__ __launch_bounds__(256) void agg2_kernel(const int* __restrict__ off,
                                                   const int* __restrict__ offE,
                                                   const unsigned short* __restrict__ col,
                                                   const float* __restrict__ as2,
                                                   const float* __restrict__ ad2,
                                                   const __bf16* __restrict__ g2b,
                                                   __bf16* __restrict__ out2, int N) {
    const int w  = blockIdx.x * 16 + (threadIdx.x >> 4);   // exact fit
    const int d8 = (threadIdx.x & 15) * 8;
    const float ad2w = ad2[w];
    f32x2 acc[4];
    float z;
    {   // self-loop
        const float wt = __expf(lrelu(as2[w] + ad2w));
        const bf16x8 hv = *(const bf16x8*)&g2b[(size_t)w * EMB + d8];
#pragma unroll
        for (int p = 0; p < 4; p++) {
            const f32x2 xf = {(float)hv[2 * p], (float)hv[2 * p + 1]};
            acc[p] = s2(wt) * xf;
        }
        z = wt;
    }
    const int jb = off[w], je = offE[w];
    int j = jb;
    for (; j + 3 < je; j += 4) {
        int s[4];
#pragma unroll
        for (int u = 0; u < 4; u++) s[u] = (int)col[j + u];
        float av[4];
#pragma unroll
        for (int u = 0; u < 4; u++) av[u] = as2[s[u]];
        bf16x8 bv[4];
#pragma unroll
        for (int u = 0; u < 4; u++)
            bv[u] = *(const bf16x8*)&g2b[(size_t)s[u] * EMB + d8];
#pragma unroll
        for (int u = 0; u < 4; u++) {
            const float wt = __expf(lrelu(av[u] + ad2w));
#pragma unroll
            for (int p = 0; p < 4; p++) {
                const f32x2 xf = {(float)bv[u][2 * p], (float)bv[u][2 * p + 1]};
                acc[p] += s2(wt) * xf;
            }
            z += wt;
        }
    }
    for (; j < je; j++) {
        const int s0 = (int)col[j];
        const float wt = __expf(lrelu(as2[s0] + ad2w));
        const bf16x8 b0 = *(const bf16x8*)&g2b[(size_t)s0 * EMB + d8];
#pragma unroll
        for (int p = 0; p < 4; p++) {
            const f32x2 xf = {(float)b0[2 * p], (float)b0[2 * p + 1]};
            acc[p] += s2(wt) * xf;
        }
        z += wt;
    }
    const float inv = 1.f / z;
    bf16x8 ov;
#pragma unroll
    for (int p = 0; p < 4; p++) {
        ov[2 * p]     = (__bf16)(acc[p][0] * inv);
        ov[2 * p + 1] = (__bf16)(acc[p][1] * inv);
    }
    *(bf16x8*)&out2[(size_t)w * EMB + d8] = ov;
}

// ---------------------------------------------------------------------------
// Global mean pool (run-length form, bf16 out2 input) + divide.
// ---------------------------------------------------------------------------
__global__ __launch_bounds__(128) void pool_kernel(const __bf16* __restrict__ out2,
                                                   const float* __restrict__ b2,
                                                   const int* __restrict__ batch,
                                                   float* __restrict__ pool,
                                                   float* __restrict__ cnt, int N) {
    const int c = threadIdx.x;
    const int n0 = blockIdx.x * 64;
    const int nend = min(n0 + 64, N);
    const float bias = b2[c];
    float acc = 0.f, cacc = 0.f;
    int curg = batch[n0];
    for (int n = n0; n < nend; n++) {
        const int g = batch[n];
        if (g != curg) {
            atomicAdd(&pool[curg * EMB + c], acc);
            if (c == 0) atomicAdd(&cnt[curg], cacc);
            acc = 0.f; cacc = 0.f; curg = g;
        }
        float v = (float)out2[(size_t)n * EMB + c] + bias;
        v = v > 0.f ? v : expm1f(v);
        acc += v;
        cacc += 1.f;
    }
    atomicAdd(&pool[curg * EMB + c], acc);
    if (c == 0) atomicAdd(&cnt[curg], cacc);
}

__global__ __launch_bounds__(256) void div_kernel(const float* __restrict__ pool,
                                                  const float* __restrict__ cnt,
                                                  float* __restrict__ out) {
    const int i = blockIdx.x * 256 + threadIdx.x;
    out[i] = pool[i] / fmaxf(cnt[i >> 7], 1.f);
}

// ---------------------------------------------------------------------------
extern "C" void kernel_launch(void* const* d_in, const int* in_sizes, int n_in,
                              void* d_out, int out_size, void* d_ws, size_t ws_size,
                              hipStream_t stream) {
    const float* x      = (const float*)d_in[0];
    const int*   ei     = (const int*)d_in[1];
    const int*   batch  = (const int*)d_in[3];
    const float* W1     = (const float*)d_in[4];
    const float* a_src1 = (const float*)d_in[5];
    const float* a_dst1 = (const float*)d_in[6];
    const float* b1     = (const float*)d_in[7];
    const float* W2     = (const float*)d_in[8];
    const float* a_src2 = (const float*)d_in[9];
    const float* a_dst2 = (const float*)d_in[10];
    const float* b2     = (const float*)d_in[11];
    float* out = (float*)d_out;

    const int N = N_NODES, E = N_EDGES;

    size_t cur_off = 0;
    auto carve = [&](size_t bytes) {
        size_t o = cur_off;
        cur_off = (cur_off + bytes + 255) & ~(size_t)255;
        return (char*)d_ws + o;
    };
    // zero-init region: pool + cnt + bcnt
    float* pool  = (float*)carve((size_t)N_GRAPHS * EMB * 4);
    float* cnt   = (float*)carve((size_t)N_GRAPHS * 4);
    int* bcnt    = (int*)carve((size_t)NBUCK * 4);
    const size_t zero_bytes = cur_off;
    int* gbase   = (int*)carve((size_t)(NBUCK + 1) * 4);
    int* gcur    = (int*)carve((size_t)NBUCK * 4);
    unsigned* stage = (unsigned*)carve((size_t)E * 4);
    float* wst   = (float*)carve((size_t)8 * IN_DIM * 4);
    __bf16* B1h  = (__bf16*)carve((size_t)HEADS * W1_FRAG * 2);
    __bf16* B1l  = (__bf16*)carve((size_t)HEADS * W1_FRAG * 2);
    __bf16* B2h  = (__bf16*)carve((size_t)F1 * EMB * 2);
    __bf16* B2l  = (__bf16*)carve((size_t)F1 * EMB * 2);
    __bf16* xb   = (__bf16*)carve((size_t)N * IN_DIM * 2);
    int* off     = (int*)carve((size_t)N * 4);
    int* offE    = (int*)carve((size_t)N * 4);
    unsigned short* col = (unsigned short*)carve((size_t)E * 2);
    float4* w4   = (float4*)carve((size_t)E * 16);
    __bf16* g2b  = (__bf16*)carve((size_t)N * EMB * 2);
    __bf16* out2 = (__bf16*)carve((size_t)N * EMB * 2);
    float* as1   = (float*)carve((size_t)N * HEADS * 4);
    float* ad1   = (float*)carve((size_t)N * HEADS * 4);
    float* as2   = (float*)carve((size_t)N * 4);
    float* ad2   = (float*)carve((size_t)N * 4);

    hipMemsetAsync(d_ws, 0, zero_bytes, stream);

    // prep: bucket histogram + weight packs + wst
    prep_kernel<<<P1_BLOCKS + 36, 256, 0, stream>>>(
        ei, bcnt, W1, B1h, B1l, W2, B2h, B2l, a_src1, a_dst1, wst);

    // 196-entry bucket scan
    scan196_kernel<<<1, 256, 0, stream>>>(bcnt, gbase, gcur);

    // rank-8 logit projection + xb emit + single-pass bucketed append
    proj_append_kernel<<<AS_BLOCKS + P1_BLOCKS, 256, 0, stream>>>(
        x, wst, as1, ad1, xb, ei, gcur, stage);

    // per-bucket CSR build (off/offE) + col(u16)/w4 placement via LDS cursors
    distribute_kernel<<<NBUCK, 256, 0, stream>>>(stage, gbase, as1, ad1,
                                                 off, offE, col, w4, N);

    // fused: gather-aggregate -> (@W1 -> ELU -> @W2) + alpha2
    agg_gemm12_kernel<<<AGG12_BLOCKS, 256, 0, stream>>>(off, offE, col, w4, xb,
                                                        as1, ad1, B1h, B1l, b1,
                                                        B2h, B2l, a_src2, a_dst2,
                                                        g2b, as2, ad2, N);

    // layer-2 aggregation (bf16 out2), then run-length pool + divide
    agg2_kernel<<<AGG12_BLOCKS, 256, 0, stream>>>(off, offE, col, as2, ad2,
                                                  g2b, out2, N);

    pool_kernel<<<(N + 63) / 64, 128, 0, stream>>>(out2, b2, batch, pool, cnt, N);
    div_kernel<<<(N_GRAPHS * EMB) / 256, 256, 0, stream>>>(pool, cnt, out);
}